// Round 8
// baseline (277.084 us; speedup 1.0000x reference)
//
#include <hip/hip_runtime.h>
#include <math.h>

#define Bb 16
#define Cn 256
#define Cs 32
#define Nn 4096   // 64*64
#define Np 1024   // 32*32
#define Ww 64
#define MS2 16    // rowstats m-splits

// attn tile params
#define MT 64
#define NT2 128

// conv_v_pool LDS tile o-stride (shorts)
#define PO 136
// conv_qk LDS q-tile stride (shorts)
#define QKPAD 36

#define C20L 28.8539008f   // 20 * log2(e)
#define L2E  1.44269504f

typedef __attribute__((ext_vector_type(8))) short short8;
typedef __attribute__((ext_vector_type(4))) float f32x4;

__device__ inline float fexp2(float x) { return __builtin_amdgcn_exp2f(x); }
__device__ inline float flog2(float x) { return __builtin_amdgcn_logf(x); }

__device__ inline short f2bf(float f) {
    unsigned u = __builtin_bit_cast(unsigned, f);
    u += 0x7fff + ((u >> 16) & 1);   // round-to-nearest-even
    return (short)(u >> 16);
}
__device__ inline float bf2f(short s) {
    unsigned u = ((unsigned)(unsigned short)s) << 16;
    return __builtin_bit_cast(float, u);
}
// packed f32 pair -> bf16x2 (RNE) via HW instruction
__device__ inline unsigned pk2bf(float lo, float hi) {
    unsigned r;
    asm("v_cvt_pk_bf16_f32 %0, %1, %2" : "=v"(r) : "v"(lo), "v"(hi));
    return r;
}
__device__ inline unsigned bfmax4(unsigned u0, unsigned u1, unsigned u2, unsigned u3) {
    float l = fmaxf(fmaxf(__builtin_bit_cast(float, u0 << 16),
                          __builtin_bit_cast(float, u1 << 16)),
                    fmaxf(__builtin_bit_cast(float, u2 << 16),
                          __builtin_bit_cast(float, u3 << 16)));
    float h = fmaxf(fmaxf(__builtin_bit_cast(float, u0 & 0xffff0000u),
                          __builtin_bit_cast(float, u1 & 0xffff0000u)),
                    fmaxf(__builtin_bit_cast(float, u2 & 0xffff0000u),
                          __builtin_bit_cast(float, u3 & 0xffff0000u)));
    return (__builtin_bit_cast(unsigned, h) & 0xffff0000u) |
           (__builtin_bit_cast(unsigned, l) >> 16);
}

// ---------------- fused weight prep: all 4 weights -> bf16 -----------------
// wq is pre-scaled by log2(e) (exp2 softmax rebasing)
__global__ void wprep_k(const float* __restrict__ wq, const float* __restrict__ wk,
                        const float* __restrict__ wv, const float* __restrict__ wo,
                        short* __restrict__ wqBf, short* __restrict__ wkBf,
                        short* __restrict__ wvBf, short* __restrict__ woBf) {
    int idx = blockIdx.x * 256 + threadIdx.x;
    if (idx < 8192)        wqBf[idx] = f2bf(wq[idx] * L2E);
    else if (idx < 16384)  wkBf[idx - 8192] = f2bf(wk[idx - 8192]);
    else if (idx < 81920)  wvBf[idx - 16384] = f2bf(wv[idx - 16384]);
    else if (idx < 147456) woBf[idx - 81920] = f2bf(wo[idx - 81920]);
}

// ---------------- x[b][c][m] f32 -> xbfT[b][m][c] bf16 (LDS transpose) -----
__global__ __launch_bounds__(256) void xpose_bf(const float* __restrict__ x,
                                                short* __restrict__ xbfT) {
    __shared__ float T[64][65];
    int lane = threadIdx.x & 63, g = threadIdx.x >> 6;
    int b = blockIdx.z, c0 = blockIdx.y * 64, m0 = blockIdx.x * 64;
    const float* xb = x + ((size_t)b * Cn + c0) * Nn + m0;
#pragma unroll
    for (int r = 0; r < 16; ++r) {
        int c_l = r * 4 + g;
        T[c_l][lane] = xb[(size_t)c_l * Nn + lane];
    }
    __syncthreads();
    short* ob = xbfT + ((size_t)b * Nn + m0) * Cn + c0;
#pragma unroll
    for (int r = 0; r < 16; ++r) {
        int m_l = r * 4 + g;
        ob[(size_t)m_l * Cn + lane] = f2bf(T[lane][m_l]);
    }
}

// ---- fused convs: blocks 0..511 = Q/K conv (+Q pool); 512..1535 = V conv+pool
__global__ __launch_bounds__(256) void convs_k(
    const short* __restrict__ xbfT, const short* __restrict__ wqBf,
    const short* __restrict__ wkBf, const float* __restrict__ bq,
    const float* __restrict__ bk, const short* __restrict__ wvBf,
    const float* __restrict__ bv, short* __restrict__ KT,
    short* __restrict__ QpT, short* __restrict__ VpT) {
    __shared__ short T[128 * PO];   // 34.8 KB (qk path uses prefix, stride QKPAD)
    int lane = threadIdx.x & 63;
    int wave = __builtin_amdgcn_readfirstlane(threadIdx.x >> 6);
    int l16 = lane & 15, quad = lane >> 4;
    int bid = blockIdx.x;

    if (bid < 512) {
        // ---------------- Q/K conv via MFMA + Q 2x2 maxpool ----------------
        int h = bid & 31, b = bid >> 5;
        int m0 = h * 128 + (wave >> 1) * 64;
        int isK = wave & 1;
        const short* wB = isK ? wkBf : wqBf;
        const float* bias = isK ? bk : bq;
        float bs = isK ? 1.f : L2E;
        const short* Arow = wB + (size_t)l16 * Cn + quad * 8;
        const short* Brow = xbfT + ((size_t)b * Nn + m0 + l16) * Cn + quad * 8;
        f32x4 acc[2][4];
#pragma unroll
        for (int i = 0; i < 2; ++i)
#pragma unroll
            for (int j = 0; j < 4; ++j) acc[i][j] = (f32x4){0.f, 0.f, 0.f, 0.f};
        for (int kk = 0; kk < Cn; kk += 32) {
            short8 af[2], bf[4];
#pragma unroll
            for (int fo = 0; fo < 2; ++fo)
                af[fo] = *(const short8*)(Arow + (size_t)(fo * 16) * Cn + kk);
#pragma unroll
            for (int fm = 0; fm < 4; ++fm)
                bf[fm] = *(const short8*)(Brow + (size_t)(fm * 16) * Cn + kk);
#pragma unroll
            for (int fo = 0; fo < 2; ++fo)
#pragma unroll
                for (int fm = 0; fm < 4; ++fm)
                    acc[fo][fm] = __builtin_amdgcn_mfma_f32_16x16x32_bf16(
                        af[fo], bf[fm], acc[fo][fm], 0, 0, 0);
        }
#pragma unroll
        for (int fo = 0; fo < 2; ++fo) {
            int c0 = fo * 16 + quad * 4;
            float b0 = bias[c0] * bs, b1 = bias[c0 + 1] * bs;
            float b2 = bias[c0 + 2] * bs, b3 = bias[c0 + 3] * bs;
#pragma unroll
            for (int fm = 0; fm < 4; ++fm) {
                int m_rel = (wave >> 1) * 64 + fm * 16 + l16;
                unsigned lo = pk2bf(acc[fo][fm][0] + b0, acc[fo][fm][1] + b1);
                unsigned hi = pk2bf(acc[fo][fm][2] + b2, acc[fo][fm][3] + b3);
                if (isK) {
                    int m = h * 128 + m_rel;
                    *(uint2*)&KT[((size_t)b * Nn + m) * Cs + c0] = make_uint2(lo, hi);
                } else {
                    *(uint2*)&T[m_rel * QKPAD + c0] = make_uint2(lo, hi);
                }
            }
        }
        __syncthreads();
        int pw = threadIdx.x >> 3;
        int cs = (threadIdx.x & 7) * 4;
        uint2 A0 = *(const uint2*)&T[(2 * pw) * QKPAD + cs];
        uint2 A1 = *(const uint2*)&T[(2 * pw + 1) * QKPAD + cs];
        uint2 A2 = *(const uint2*)&T[(64 + 2 * pw) * QKPAD + cs];
        uint2 A3 = *(const uint2*)&T[(64 + 2 * pw + 1) * QKPAD + cs];
        unsigned w0 = bfmax4(A0.x, A1.x, A2.x, A3.x);
        unsigned w1 = bfmax4(A0.y, A1.y, A2.y, A3.y);
        *(uint2*)&QpT[((size_t)b * Np + h * 32 + pw) * Cs + cs] = make_uint2(w0, w1);
    } else {
        // ---------------- V conv via MFMA + bias + 2x2 maxpool -------------
        bid -= 512;
        int h = bid & 31, oy = (bid >> 5) & 1, b = bid >> 6;
        int m0 = h * 128 + (wave >> 1) * 64;
        int o0 = oy * 128 + (wave & 1) * 64;
        const short* Arow = wvBf + (size_t)(o0 + l16) * Cn + quad * 8;
        const short* Brow = xbfT + ((size_t)b * Nn + m0 + l16) * Cn + quad * 8;
        f32x4 acc[4][4];
#pragma unroll
        for (int i = 0; i < 4; ++i)
#pragma unroll
            for (int j = 0; j < 4; ++j) acc[i][j] = (f32x4){0.f, 0.f, 0.f, 0.f};
        for (int kk = 0; kk < Cn; kk += 32) {
            short8 af[4], bf[4];
#pragma unroll
            for (int fo = 0; fo < 4; ++fo)
                af[fo] = *(const short8*)(Arow + (size_t)(fo * 16) * Cn + kk);
#pragma unroll
            for (int fm = 0; fm < 4; ++fm)
                bf[fm] = *(const short8*)(Brow + (size_t)(fm * 16) * Cn + kk);
#pragma unroll
            for (int fo = 0; fo < 4; ++fo)
#pragma unroll
                for (int fm = 0; fm < 4; ++fm)
                    acc[fo][fm] = __builtin_amdgcn_mfma_f32_16x16x32_bf16(
                        af[fo], bf[fm], acc[fo][fm], 0, 0, 0);
        }
#pragma unroll
        for (int fo = 0; fo < 4; ++fo) {
            int o_loc = (wave & 1) * 64 + fo * 16 + quad * 4;
            int o_g = oy * 128 + o_loc;
            float b0 = bv[o_g], b1 = bv[o_g + 1], b2 = bv[o_g + 2], b3 = bv[o_g + 3];
#pragma unroll
            for (int fm = 0; fm < 4; ++fm) {
                int m_rel = (wave >> 1) * 64 + fm * 16 + l16;
                unsigned lo = pk2bf(acc[fo][fm][0] + b0, acc[fo][fm][1] + b1);
                unsigned hi = pk2bf(acc[fo][fm][2] + b2, acc[fo][fm][3] + b3);
                *(uint2*)&T[m_rel * PO + o_loc] = make_uint2(lo, hi);
            }
        }
        __syncthreads();
#pragma unroll
        for (int rep = 0; rep < 2; ++rep) {
            int t = threadIdx.x + rep * 256;
            int cg = t & 15;
            int pw = t >> 4;
            const short* r0 = &T[(2 * pw) * PO + cg * 8];
            const short* r1 = r0 + PO;
            const short* r2 = &T[(64 + 2 * pw) * PO + cg * 8];
            const short* r3 = r2 + PO;
            short8 a = *(const short8*)r0, b8 = *(const short8*)r1;
            short8 c8 = *(const short8*)r2, d8 = *(const short8*)r3;
            short8 o8;
#pragma unroll
            for (int j = 0; j < 8; ++j) {
                float v = fmaxf(fmaxf(bf2f(a[j]), bf2f(b8[j])),
                                fmaxf(bf2f(c8[j]), bf2f(d8[j])));
                o8[j] = f2bf(v);
            }
            int n = h * 32 + pw;
            *(short8*)(VpT + ((size_t)b * Np + n) * Cn + oy * 128 + cg * 8) = o8;
        }
    }
}

// ---- fused: blocks 0..1023 = rowstats (sum exp2); 1024..1279 = vo GEMM ----
__global__ __launch_bounds__(256) void stats_vo_k(
    const short* __restrict__ KT, const short* __restrict__ QpT,
    float* __restrict__ pS, const short* __restrict__ VpT,
    const short* __restrict__ woBf, short* __restrict__ VoBf) {
    int lane = threadIdx.x & 63;
    int wave = __builtin_amdgcn_readfirstlane(threadIdx.x >> 6);
    int l16 = lane & 15, quad = lane >> 4;
    int bid = blockIdx.x;

    if (bid < 1024) {
        // ------------------ rowstats: sum of exp2(e' - C20L) ---------------
        int nx = bid & 3, b = (bid >> 2) & 15, ms = bid >> 6;
        int nbase = nx * 256 + wave * 64;
        short8 af[4];
#pragma unroll
        for (int nf = 0; nf < 4; ++nf)
            af[nf] = *(const short8*)(QpT +
                ((size_t)b * Np + nbase + nf * 16 + l16) * Cs + quad * 8);
        float Sv[4][4];
#pragma unroll
        for (int nf = 0; nf < 4; ++nf)
#pragma unroll
            for (int r = 0; r < 4; ++r) Sv[nf][r] = 0.f;
        int m0 = ms * (Nn / MS2);
        for (int mm = 0; mm < Nn / MS2; mm += 16) {
            short8 bf = *(const short8*)(KT +
                ((size_t)b * Nn + m0 + mm + l16) * Cs + quad * 8);
#pragma unroll
            for (int nf = 0; nf < 4; ++nf) {
                f32x4 e = __builtin_amdgcn_mfma_f32_16x16x32_bf16(
                    af[nf], bf, (f32x4){0.f, 0.f, 0.f, 0.f}, 0, 0, 0);
#pragma unroll
                for (int r = 0; r < 4; ++r)
                    Sv[nf][r] += fexp2(e[r] - C20L);
            }
        }
#pragma unroll
        for (int nf = 0; nf < 4; ++nf)
#pragma unroll
            for (int r = 0; r < 4; ++r) {
                float S = Sv[nf][r];
#pragma unroll
                for (int s = 1; s <= 8; s <<= 1) S += __shfl_xor(S, s);
                Sv[nf][r] = S;
            }
        if (l16 == 0) {
#pragma unroll
            for (int nf = 0; nf < 4; ++nf)
#pragma unroll
                for (int r = 0; r < 4; ++r) {
                    size_t o = ((size_t)ms * Bb + b) * Np + nbase + nf * 16 +
                               quad * 4 + r;
                    pS[o] = Sv[nf][r];
                }
        }
    } else {
        // ------------------ V' = wo @ Vp via MFMA --------------------------
        bid -= 1024;
        int nx = bid & 7, oy = (bid >> 3) & 1, b = bid >> 4;
        int n0 = nx * 128 + (wave >> 1) * 64;
        int o0 = oy * 128 + (wave & 1) * 64;
        const short* Arow = woBf + (size_t)(o0 + l16) * Cn + quad * 8;
        const short* Brow = VpT + ((size_t)b * Np + n0 + l16) * Cn + quad * 8;
        f32x4 acc[4][4];
#pragma unroll
        for (int i = 0; i < 4; ++i)
#pragma unroll
            for (int j = 0; j < 4; ++j) acc[i][j] = (f32x4){0.f, 0.f, 0.f, 0.f};
        for (int kk = 0; kk < Cn; kk += 32) {
            short8 af[4], bf[4];
#pragma unroll
            for (int fo = 0; fo < 4; ++fo)
                af[fo] = *(const short8*)(Arow + (size_t)(fo * 16) * Cn + kk);
#pragma unroll
            for (int fm = 0; fm < 4; ++fm)
                bf[fm] = *(const short8*)(Brow + (size_t)(fm * 16) * Cn + kk);
#pragma unroll
            for (int fo = 0; fo < 4; ++fo)
#pragma unroll
                for (int fm = 0; fm < 4; ++fm)
                    acc[fo][fm] = __builtin_amdgcn_mfma_f32_16x16x32_bf16(
                        af[fo], bf[fm], acc[fo][fm], 0, 0, 0);
        }
#pragma unroll
        for (int fo = 0; fo < 4; ++fo)
#pragma unroll
            for (int fm = 0; fm < 4; ++fm) {
                int n = n0 + fm * 16 + l16;
#pragma unroll
                for (int r = 0; r < 4; ++r) {
                    int o = o0 + fo * 16 + quad * 4 + r;
                    VoBf[((size_t)b * Cn + o) * Np + n] = f2bf(acc[fo][fm][r]);
                }
            }
    }
}

// ---- combine partials -> Ae[b][n] = C20L + log2(S) ------------------------
__global__ void comb_k(const float* __restrict__ pS, float* __restrict__ Ae) {
    int gidx = blockIdx.x * 256 + threadIdx.x;   // Bb*Np
    int b = gidx >> 10, n = gidx & (Np - 1);
    float S = 0.f;
#pragma unroll
    for (int ms = 0; ms < MS2; ++ms)
        S += pS[((size_t)ms * Bb + b) * Np + n];
    Ae[(size_t)b * Np + n] = C20L + flog2(S);
}

// ---- fused attention out: PV(t) FIRST, then E(t+1) (LDS is in-order/wave) --
__global__ __launch_bounds__(512) void attn_out_k(
    const short* __restrict__ KT, const short* __restrict__ QpT,
    const short* __restrict__ VoBf, const float* __restrict__ Ae,
    const float* __restrict__ bo, const float* __restrict__ gamma,
    const float* __restrict__ x, float* __restrict__ out) {
    __shared__ short P[2][MT * 128];   // 2 x 16 KB, XOR-swizzled rows
    int tid  = threadIdx.x;
    int lane = tid & 63;
    int wave = __builtin_amdgcn_readfirstlane(tid >> 6);   // 0..7
    int l16 = lane & 15, quad = lane >> 4;

    // XCD-aware decode: each XCD keeps 2 batches -> VoBf[b] stays L2-resident
    int bid = blockIdx.x;
    int xcd = bid & 7;
    int idx = bid >> 3;               // 0..127
    int b   = xcd + 8 * (idx >> 6);   // {xcd, xcd+8}
    int m0  = (idx & 63) * MT;

    const short* QT = QpT + (size_t)b * Np * Cs;
    const short* Kb = KT + ((size_t)b * Nn + m0) * Cs;
    const short* Vb = VoBf + ((size_t)b * Cn + wave * 32) * Np;
    const float* Ab = Ae + (size_t)b * Np;

    short8 kf[4];
#pragma unroll
    for (int mf = 0; mf < 4; ++mf)
        kf[mf] = *(const short8*)(Kb + (size_t)(mf * 16 + l16) * Cs + quad * 8);

    f32x4 acc[2][4];
#pragma unroll
    for (int i = 0; i < 2; ++i)
#pragma unroll
        for (int j = 0; j < 4; ++j) acc[i][j] = (f32x4){0.f, 0.f, 0.f, 0.f};

    auto Ephase = [&](int t) {
        int buf = t & 1;
        int nb = t * NT2 + wave * 16;     // wave's 16-n strip
        short8 qf = *(const short8*)(QT + (size_t)(nb + l16) * Cs + quad * 8);
        f32x4 av = *(const f32x4*)&Ab[nb + quad * 4];
#pragma unroll
        for (int mf = 0; mf < 4; ++mf) {
            f32x4 e = __builtin_amdgcn_mfma_f32_16x16x32_bf16(
                qf, kf[mf], (f32x4){0.f, 0.f, 0.f, 0.f}, 0, 0, 0);
            float p0 = fexp2(e[0] - av[0]);
            float p1 = fexp2(e[1] - av[1]);
            float p2 = fexp2(e[2] - av[2]);
            float p3 = fexp2(e[3] - av[3]);
            unsigned p01 = pk2bf(p0, p1);
            unsigned p23 = pk2bf(p2, p3);
            int m_l = mf * 16 + l16;
            int n_l = wave * 16 + quad * 4;
            int si = (m_l * 128 + n_l) ^ ((m_l & 7) << 3);   // XOR swizzle
            *(uint2*)&P[buf][si] = make_uint2(p01, p23);
        }
    };

    Ephase(0);
    __syncthreads();
    for (int t = 0; t < 8; ++t) {
        // ---- PV(t) FIRST: ds_reads issue right after the barrier ----
        const short* At = Vb + t * NT2;
        int buf = t & 1;
#pragma unroll
        for (int kk = 0; kk < NT2; kk += 32) {
            short8 bfr[4], afr[2];
#pragma unroll
            for (int fm = 0; fm < 4; ++fm) {
                int row = fm * 16 + l16;
                int si = (row * 128 + kk + quad * 8) ^ ((l16 & 7) << 3);
                bfr[fm] = *(const short8*)&P[buf][si];
            }
#pragma unroll
            for (int fo = 0; fo < 2; ++fo)
                afr[fo] = *(const short8*)(At + (size_t)(fo * 16 + l16) * Np +
                                           kk + quad * 8);
            __builtin_amdgcn_s_setprio(1);
#pragma unroll
            for (int fo = 0; fo < 2; ++fo)
#pragma unroll
                for (int fm = 0; fm < 4; ++fm)
                    acc[fo][fm] = __builtin_amdgcn_mfma_f32_16x16x32_bf16(
                        afr[fo], bfr[fm], acc[fo][fm], 0, 0, 0);
            __builtin_amdgcn_s_setprio(0);
        }
        // ---- then E(t+1): its ds_writes queue AFTER PV's reads ----
        if (t < 7) Ephase(t + 1);
        __syncthreads();
    }
    // ---- epilogue ----
    float g = gamma[0];
#pragma unroll
    for (int fo = 0; fo < 2; ++fo)
#pragma unroll
        for (int fm = 0; fm < 4; ++fm) {
            int m = m0 + fm * 16 + l16;
#pragma unroll
            for (int r = 0; r < 4; ++r) {
                int o = wave * 32 + fo * 16 + quad * 4 + r;
                size_t idx2 = ((size_t)b * Cn + o) * Nn + m;
                out[idx2] = g * (acc[fo][fm][r] + bo[o]) + x[idx2];
            }
        }
}

extern "C" void kernel_launch(void* const* d_in, const int* in_sizes, int n_in,
                              void* d_out, int out_size, void* d_ws, size_t ws_size,
                              hipStream_t stream) {
    (void)in_sizes; (void)n_in; (void)out_size; (void)ws_size;
    const float* x     = (const float*)d_in[0];
    const float* wq    = (const float*)d_in[1];
    const float* bq    = (const float*)d_in[2];
    const float* wk    = (const float*)d_in[3];
    const float* bk    = (const float*)d_in[4];
    const float* wv    = (const float*)d_in[5];
    const float* bv    = (const float*)d_in[6];
    const float* wo    = (const float*)d_in[7];
    const float* bo    = (const float*)d_in[8];
    const float* gamma = (const float*)d_in[9];
    float* out = (float*)d_out;

    float* ws = (float*)d_ws;
    size_t off = 0;
    short* xbfT = (short*)(ws + off); off += (size_t)Bb * Nn * Cn / 2;  // 33.5MB
    short* VpT  = (short*)(ws + off); off += (size_t)Bb * Np * Cn / 2;  //  8.4MB
    short* VoBf = (short*)(ws + off); off += (size_t)Bb * Cn * Np / 2;  //  8.4MB
    short* KT   = (short*)(ws + off); off += (size_t)Bb * Nn * Cs / 2;  //  4.2MB
    short* QpT  = (short*)(ws + off); off += (size_t)Bb * Np * Cs / 2;  //  1.0MB
    float* pS   = ws + off;           off += (size_t)MS2 * Bb * Np;
    float* Ae   = ws + off;           off += (size_t)Bb * Np;
    short* wqBf = (short*)(ws + off); off += (size_t)Cs * Cn / 2;
    short* wkBf = (short*)(ws + off); off += (size_t)Cs * Cn / 2;
    short* wvBf = (short*)(ws + off); off += (size_t)Cn * Cn / 2;
    short* woBf = (short*)(ws + off); off += (size_t)Cn * Cn / 2;

    // fused weight prep (wq pre-scaled by log2 e)
    wprep_k<<<dim3(576), 256, 0, stream>>>(wq, wk, wv, wo, wqBf, wkBf, wvBf, woBf);

    // x -> bf16 transposed [b][m][c]
    xpose_bf<<<dim3(Nn / 64, Cn / 64, Bb), 256, 0, stream>>>(x, xbfT);

    // fused Q/K conv (+Q pool) and V conv (+pool)
    convs_k<<<dim3(512 + 1024), 256, 0, stream>>>(xbfT, wqBf, wkBf, bq, bk,
                                                  wvBf, bv, KT, QpT, VpT);

    // fused rowstats + vo GEMM
    stats_vo_k<<<dim3(1024 + 256), 256, 0, stream>>>(KT, QpT, pS, VpT, woBf, VoBf);

    // combine partials -> Ae
    comb_k<<<dim3(Bb * Np / 256), 256, 0, stream>>>(pS, Ae);

    // fused attention output (PV-first ordering, setprio, XCD swizzle)
    attn_out_k<<<dim3(1024), 512, 0, stream>>>(KT, QpT, VoBf, Ae,
                                               bo, gamma, x, out);
}

// Round 10
// 269.526 us; speedup vs baseline: 1.0280x; 1.0280x over previous
//
#include <hip/hip_runtime.h>
#include <math.h>

#define Bb 16
#define Cn 256
#define Cs 32
#define Nn 4096   // 64*64
#define Np 1024   // 32*32
#define Ww 64
#define MS2 16    // rowstats m-splits

// attn tile params
#define MT 64
#define NT2 128

// conv_v_pool LDS tile o-stride (shorts)
#define PO 136
// conv_qk LDS q-tile stride (shorts)
#define QKPAD 36

#define C20L 28.8539008f   // 20 * log2(e)
#define L2E  1.44269504f

typedef __attribute__((ext_vector_type(8))) short short8;
typedef __attribute__((ext_vector_type(4))) float f32x4;

__device__ inline float fexp2(float x) { return __builtin_amdgcn_exp2f(x); }
__device__ inline float flog2(float x) { return __builtin_amdgcn_logf(x); }

__device__ inline short f2bf(float f) {
    unsigned u = __builtin_bit_cast(unsigned, f);
    u += 0x7fff + ((u >> 16) & 1);   // round-to-nearest-even
    return (short)(u >> 16);
}
__device__ inline float bf2f(short s) {
    unsigned u = ((unsigned)(unsigned short)s) << 16;
    return __builtin_bit_cast(float, u);
}
// packed f32 pair -> bf16x2 (RNE) via HW instruction
__device__ inline unsigned pk2bf(float lo, float hi) {
    unsigned r;
    asm("v_cvt_pk_bf16_f32 %0, %1, %2" : "=v"(r) : "v"(lo), "v"(hi));
    return r;
}
__device__ inline unsigned bfmax4(unsigned u0, unsigned u1, unsigned u2, unsigned u3) {
    float l = fmaxf(fmaxf(__builtin_bit_cast(float, u0 << 16),
                          __builtin_bit_cast(float, u1 << 16)),
                    fmaxf(__builtin_bit_cast(float, u2 << 16),
                          __builtin_bit_cast(float, u3 << 16)));
    float h = fmaxf(fmaxf(__builtin_bit_cast(float, u0 & 0xffff0000u),
                          __builtin_bit_cast(float, u1 & 0xffff0000u)),
                    fmaxf(__builtin_bit_cast(float, u2 & 0xffff0000u),
                          __builtin_bit_cast(float, u3 & 0xffff0000u)));
    return (__builtin_bit_cast(unsigned, h) & 0xffff0000u) |
           (__builtin_bit_cast(unsigned, l) >> 16);
}

// ---------------- fused weight prep: all 4 weights -> bf16 -----------------
// wq is pre-scaled by log2(e) (exp2 softmax rebasing)
__global__ void wprep_k(const float* __restrict__ wq, const float* __restrict__ wk,
                        const float* __restrict__ wv, const float* __restrict__ wo,
                        short* __restrict__ wqBf, short* __restrict__ wkBf,
                        short* __restrict__ wvBf, short* __restrict__ woBf) {
    int idx = blockIdx.x * 256 + threadIdx.x;
    if (idx < 8192)        wqBf[idx] = f2bf(wq[idx] * L2E);
    else if (idx < 16384)  wkBf[idx - 8192] = f2bf(wk[idx - 8192]);
    else if (idx < 81920)  wvBf[idx - 16384] = f2bf(wv[idx - 16384]);
    else if (idx < 147456) woBf[idx - 81920] = f2bf(wo[idx - 81920]);
}

// ---------------- x[b][c][m] f32 -> xbfT[b][m][c] bf16 (LDS transpose) -----
__global__ __launch_bounds__(256) void xpose_bf(const float* __restrict__ x,
                                                short* __restrict__ xbfT) {
    __shared__ float T[64][65];
    int lane = threadIdx.x & 63, g = threadIdx.x >> 6;
    int b = blockIdx.z, c0 = blockIdx.y * 64, m0 = blockIdx.x * 64;
    const float* xb = x + ((size_t)b * Cn + c0) * Nn + m0;
#pragma unroll
    for (int r = 0; r < 16; ++r) {
        int c_l = r * 4 + g;
        T[c_l][lane] = xb[(size_t)c_l * Nn + lane];
    }
    __syncthreads();
    short* ob = xbfT + ((size_t)b * Nn + m0) * Cn + c0;
#pragma unroll
    for (int r = 0; r < 16; ++r) {
        int m_l = r * 4 + g;
        ob[(size_t)m_l * Cn + lane] = f2bf(T[lane][m_l]);
    }
}

// ---- fused convs: blocks 0..511 = Q/K conv (+Q pool); 512..1535 = V conv+pool
__global__ __launch_bounds__(256) void convs_k(
    const short* __restrict__ xbfT, const short* __restrict__ wqBf,
    const short* __restrict__ wkBf, const float* __restrict__ bq,
    const float* __restrict__ bk, const short* __restrict__ wvBf,
    const float* __restrict__ bv, short* __restrict__ KT,
    short* __restrict__ QpT, short* __restrict__ VpT) {
    __shared__ short T[128 * PO];   // 34.8 KB (qk path uses prefix, stride QKPAD)
    int lane = threadIdx.x & 63;
    int wave = __builtin_amdgcn_readfirstlane(threadIdx.x >> 6);
    int l16 = lane & 15, quad = lane >> 4;
    int bid = blockIdx.x;

    if (bid < 512) {
        // ---------------- Q/K conv via MFMA + Q 2x2 maxpool ----------------
        int h = bid & 31, b = bid >> 5;
        int m0 = h * 128 + (wave >> 1) * 64;
        int isK = wave & 1;
        const short* wB = isK ? wkBf : wqBf;
        const float* bias = isK ? bk : bq;
        float bs = isK ? 1.f : L2E;
        const short* Arow = wB + (size_t)l16 * Cn + quad * 8;
        const short* Brow = xbfT + ((size_t)b * Nn + m0 + l16) * Cn + quad * 8;
        f32x4 acc[2][4];
#pragma unroll
        for (int i = 0; i < 2; ++i)
#pragma unroll
            for (int j = 0; j < 4; ++j) acc[i][j] = (f32x4){0.f, 0.f, 0.f, 0.f};
        for (int kk = 0; kk < Cn; kk += 32) {
            short8 af[2], bf[4];
#pragma unroll
            for (int fo = 0; fo < 2; ++fo)
                af[fo] = *(const short8*)(Arow + (size_t)(fo * 16) * Cn + kk);
#pragma unroll
            for (int fm = 0; fm < 4; ++fm)
                bf[fm] = *(const short8*)(Brow + (size_t)(fm * 16) * Cn + kk);
#pragma unroll
            for (int fo = 0; fo < 2; ++fo)
#pragma unroll
                for (int fm = 0; fm < 4; ++fm)
                    acc[fo][fm] = __builtin_amdgcn_mfma_f32_16x16x32_bf16(
                        af[fo], bf[fm], acc[fo][fm], 0, 0, 0);
        }
#pragma unroll
        for (int fo = 0; fo < 2; ++fo) {
            int c0 = fo * 16 + quad * 4;
            float b0 = bias[c0] * bs, b1 = bias[c0 + 1] * bs;
            float b2 = bias[c0 + 2] * bs, b3 = bias[c0 + 3] * bs;
#pragma unroll
            for (int fm = 0; fm < 4; ++fm) {
                int m_rel = (wave >> 1) * 64 + fm * 16 + l16;
                unsigned lo = pk2bf(acc[fo][fm][0] + b0, acc[fo][fm][1] + b1);
                unsigned hi = pk2bf(acc[fo][fm][2] + b2, acc[fo][fm][3] + b3);
                if (isK) {
                    int m = h * 128 + m_rel;
                    *(uint2*)&KT[((size_t)b * Nn + m) * Cs + c0] = make_uint2(lo, hi);
                } else {
                    *(uint2*)&T[m_rel * QKPAD + c0] = make_uint2(lo, hi);
                }
            }
        }
        __syncthreads();
        int pw = threadIdx.x >> 3;
        int cs = (threadIdx.x & 7) * 4;
        uint2 A0 = *(const uint2*)&T[(2 * pw) * QKPAD + cs];
        uint2 A1 = *(const uint2*)&T[(2 * pw + 1) * QKPAD + cs];
        uint2 A2 = *(const uint2*)&T[(64 + 2 * pw) * QKPAD + cs];
        uint2 A3 = *(const uint2*)&T[(64 + 2 * pw + 1) * QKPAD + cs];
        unsigned w0 = bfmax4(A0.x, A1.x, A2.x, A3.x);
        unsigned w1 = bfmax4(A0.y, A1.y, A2.y, A3.y);
        *(uint2*)&QpT[((size_t)b * Np + h * 32 + pw) * Cs + cs] = make_uint2(w0, w1);
    } else {
        // ---------------- V conv via MFMA + bias + 2x2 maxpool -------------
        bid -= 512;
        int h = bid & 31, oy = (bid >> 5) & 1, b = bid >> 6;
        int m0 = h * 128 + (wave >> 1) * 64;
        int o0 = oy * 128 + (wave & 1) * 64;
        const short* Arow = wvBf + (size_t)(o0 + l16) * Cn + quad * 8;
        const short* Brow = xbfT + ((size_t)b * Nn + m0 + l16) * Cn + quad * 8;
        f32x4 acc[4][4];
#pragma unroll
        for (int i = 0; i < 4; ++i)
#pragma unroll
            for (int j = 0; j < 4; ++j) acc[i][j] = (f32x4){0.f, 0.f, 0.f, 0.f};
        for (int kk = 0; kk < Cn; kk += 32) {
            short8 af[4], bf[4];
#pragma unroll
            for (int fo = 0; fo < 4; ++fo)
                af[fo] = *(const short8*)(Arow + (size_t)(fo * 16) * Cn + kk);
#pragma unroll
            for (int fm = 0; fm < 4; ++fm)
                bf[fm] = *(const short8*)(Brow + (size_t)(fm * 16) * Cn + kk);
#pragma unroll
            for (int fo = 0; fo < 4; ++fo)
#pragma unroll
                for (int fm = 0; fm < 4; ++fm)
                    acc[fo][fm] = __builtin_amdgcn_mfma_f32_16x16x32_bf16(
                        af[fo], bf[fm], acc[fo][fm], 0, 0, 0);
        }
#pragma unroll
        for (int fo = 0; fo < 4; ++fo) {
            int o_loc = (wave & 1) * 64 + fo * 16 + quad * 4;
            int o_g = oy * 128 + o_loc;
            float b0 = bv[o_g], b1 = bv[o_g + 1], b2 = bv[o_g + 2], b3 = bv[o_g + 3];
#pragma unroll
            for (int fm = 0; fm < 4; ++fm) {
                int m_rel = (wave >> 1) * 64 + fm * 16 + l16;
                unsigned lo = pk2bf(acc[fo][fm][0] + b0, acc[fo][fm][1] + b1);
                unsigned hi = pk2bf(acc[fo][fm][2] + b2, acc[fo][fm][3] + b3);
                *(uint2*)&T[m_rel * PO + o_loc] = make_uint2(lo, hi);
            }
        }
        __syncthreads();
#pragma unroll
        for (int rep = 0; rep < 2; ++rep) {
            int t = threadIdx.x + rep * 256;
            int cg = t & 15;
            int pw = t >> 4;
            const short* r0 = &T[(2 * pw) * PO + cg * 8];
            const short* r1 = r0 + PO;
            const short* r2 = &T[(64 + 2 * pw) * PO + cg * 8];
            const short* r3 = r2 + PO;
            short8 a = *(const short8*)r0, b8 = *(const short8*)r1;
            short8 c8 = *(const short8*)r2, d8 = *(const short8*)r3;
            short8 o8;
#pragma unroll
            for (int j = 0; j < 8; ++j) {
                float v = fmaxf(fmaxf(bf2f(a[j]), bf2f(b8[j])),
                                fmaxf(bf2f(c8[j]), bf2f(d8[j])));
                o8[j] = f2bf(v);
            }
            int n = h * 32 + pw;
            *(short8*)(VpT + ((size_t)b * Np + n) * Cn + oy * 128 + cg * 8) = o8;
        }
    }
}

// ---- fused: blocks 0..1023 = rowstats (sum exp2); 1024..1279 = vo GEMM ----
__global__ __launch_bounds__(256) void stats_vo_k(
    const short* __restrict__ KT, const short* __restrict__ QpT,
    float* __restrict__ pS, const short* __restrict__ VpT,
    const short* __restrict__ woBf, short* __restrict__ VoBf) {
    int lane = threadIdx.x & 63;
    int wave = __builtin_amdgcn_readfirstlane(threadIdx.x >> 6);
    int l16 = lane & 15, quad = lane >> 4;
    int bid = blockIdx.x;

    if (bid < 1024) {
        // ------------------ rowstats: sum of exp2(e' - C20L) ---------------
        int nx = bid & 3, b = (bid >> 2) & 15, ms = bid >> 6;
        int nbase = nx * 256 + wave * 64;
        short8 af[4];
#pragma unroll
        for (int nf = 0; nf < 4; ++nf)
            af[nf] = *(const short8*)(QpT +
                ((size_t)b * Np + nbase + nf * 16 + l16) * Cs + quad * 8);
        float Sv[4][4];
#pragma unroll
        for (int nf = 0; nf < 4; ++nf)
#pragma unroll
            for (int r = 0; r < 4; ++r) Sv[nf][r] = 0.f;
        int m0 = ms * (Nn / MS2);
        for (int mm = 0; mm < Nn / MS2; mm += 16) {
            short8 bf = *(const short8*)(KT +
                ((size_t)b * Nn + m0 + mm + l16) * Cs + quad * 8);
#pragma unroll
            for (int nf = 0; nf < 4; ++nf) {
                f32x4 e = __builtin_amdgcn_mfma_f32_16x16x32_bf16(
                    af[nf], bf, (f32x4){0.f, 0.f, 0.f, 0.f}, 0, 0, 0);
#pragma unroll
                for (int r = 0; r < 4; ++r)
                    Sv[nf][r] += fexp2(e[r] - C20L);
            }
        }
#pragma unroll
        for (int nf = 0; nf < 4; ++nf)
#pragma unroll
            for (int r = 0; r < 4; ++r) {
                float S = Sv[nf][r];
#pragma unroll
                for (int s = 1; s <= 8; s <<= 1) S += __shfl_xor(S, s);
                Sv[nf][r] = S;
            }
        if (l16 == 0) {
#pragma unroll
            for (int nf = 0; nf < 4; ++nf)
#pragma unroll
                for (int r = 0; r < 4; ++r) {
                    size_t o = ((size_t)ms * Bb + b) * Np + nbase + nf * 16 +
                               quad * 4 + r;
                    pS[o] = Sv[nf][r];
                }
        }
    } else {
        // ------------------ V' = wo @ Vp via MFMA --------------------------
        bid -= 1024;
        int nx = bid & 7, oy = (bid >> 3) & 1, b = bid >> 4;
        int n0 = nx * 128 + (wave >> 1) * 64;
        int o0 = oy * 128 + (wave & 1) * 64;
        const short* Arow = woBf + (size_t)(o0 + l16) * Cn + quad * 8;
        const short* Brow = VpT + ((size_t)b * Np + n0 + l16) * Cn + quad * 8;
        f32x4 acc[4][4];
#pragma unroll
        for (int i = 0; i < 4; ++i)
#pragma unroll
            for (int j = 0; j < 4; ++j) acc[i][j] = (f32x4){0.f, 0.f, 0.f, 0.f};
        for (int kk = 0; kk < Cn; kk += 32) {
            short8 af[4], bf[4];
#pragma unroll
            for (int fo = 0; fo < 4; ++fo)
                af[fo] = *(const short8*)(Arow + (size_t)(fo * 16) * Cn + kk);
#pragma unroll
            for (int fm = 0; fm < 4; ++fm)
                bf[fm] = *(const short8*)(Brow + (size_t)(fm * 16) * Cn + kk);
#pragma unroll
            for (int fo = 0; fo < 4; ++fo)
#pragma unroll
                for (int fm = 0; fm < 4; ++fm)
                    acc[fo][fm] = __builtin_amdgcn_mfma_f32_16x16x32_bf16(
                        af[fo], bf[fm], acc[fo][fm], 0, 0, 0);
        }
#pragma unroll
        for (int fo = 0; fo < 4; ++fo)
#pragma unroll
            for (int fm = 0; fm < 4; ++fm) {
                int n = n0 + fm * 16 + l16;
#pragma unroll
                for (int r = 0; r < 4; ++r) {
                    int o = o0 + fo * 16 + quad * 4 + r;
                    VoBf[((size_t)b * Cn + o) * Np + n] = f2bf(acc[fo][fm][r]);
                }
            }
    }
}

// ---- combine partials -> Ae[b][n] = C20L + log2(S) ------------------------
__global__ void comb_k(const float* __restrict__ pS, float* __restrict__ Ae) {
    int gidx = blockIdx.x * 256 + threadIdx.x;   // Bb*Np
    int b = gidx >> 10, n = gidx & (Np - 1);
    float S = 0.f;
#pragma unroll
    for (int ms = 0; ms < MS2; ++ms)
        S += pS[((size_t)ms * Bb + b) * Np + n];
    Ae[(size_t)b * Np + n] = C20L + flog2(S);
}

// ---- fused attention out: E-first (verified) + same-epoch V reg-hoist -----
__global__ __launch_bounds__(512) void attn_out_k(
    const short* __restrict__ KT, const short* __restrict__ QpT,
    const short* __restrict__ VoBf, const float* __restrict__ Ae,
    const float* __restrict__ bo, const float* __restrict__ gamma,
    const float* __restrict__ x, float* __restrict__ out) {
    __shared__ short P[2][MT * 128];   // 2 x 16 KB, XOR-swizzled rows
    int tid  = threadIdx.x;
    int lane = tid & 63;
    int wave = __builtin_amdgcn_readfirstlane(tid >> 6);   // 0..7
    int l16 = lane & 15, quad = lane >> 4;

    // XCD-aware decode: each XCD keeps 2 batches -> VoBf[b] stays L2-resident
    int bid = blockIdx.x;
    int xcd = bid & 7;
    int idx = bid >> 3;               // 0..127
    int b   = xcd + 8 * (idx >> 6);   // {xcd, xcd+8}
    int m0  = (idx & 63) * MT;

    const short* QT = QpT + (size_t)b * Np * Cs;
    const short* Kb = KT + ((size_t)b * Nn + m0) * Cs;
    const short* Vb = VoBf + ((size_t)b * Cn + wave * 32) * Np;
    const float* Ab = Ae + (size_t)b * Np;

    short8 kf[4];
#pragma unroll
    for (int mf = 0; mf < 4; ++mf)
        kf[mf] = *(const short8*)(Kb + (size_t)(mf * 16 + l16) * Cs + quad * 8);

    f32x4 acc[2][4];
#pragma unroll
    for (int i = 0; i < 2; ++i)
#pragma unroll
        for (int j = 0; j < 4; ++j) acc[i][j] = (f32x4){0.f, 0.f, 0.f, 0.f};

    auto Ephase = [&](int t) {
        int buf = t & 1;
        int nb = t * NT2 + wave * 16;     // wave's 16-n strip
        short8 qf = *(const short8*)(QT + (size_t)(nb + l16) * Cs + quad * 8);
        f32x4 av = *(const f32x4*)&Ab[nb + quad * 4];
#pragma unroll
        for (int mf = 0; mf < 4; ++mf) {
            f32x4 e = __builtin_amdgcn_mfma_f32_16x16x32_bf16(
                qf, kf[mf], (f32x4){0.f, 0.f, 0.f, 0.f}, 0, 0, 0);
            float p0 = fexp2(e[0] - av[0]);
            float p1 = fexp2(e[1] - av[1]);
            float p2 = fexp2(e[2] - av[2]);
            float p3 = fexp2(e[3] - av[3]);
            unsigned p01 = pk2bf(p0, p1);
            unsigned p23 = pk2bf(p2, p3);
            int m_l = mf * 16 + l16;
            int n_l = wave * 16 + quad * 4;
            int si = (m_l * 128 + n_l) ^ ((m_l & 7) << 3);   // XOR swizzle
            *(uint2*)&P[buf][si] = make_uint2(p01, p23);
        }
    };

    Ephase(0);
    __syncthreads();
    for (int t = 0; t < 8; ++t) {
        // ---- hoist V(t) loads: latency hides under Ephase(t+1) ----
        const short* At = Vb + t * NT2;
        short8 vf[8];
#pragma unroll
        for (int k4 = 0; k4 < 4; ++k4)
#pragma unroll
            for (int fo = 0; fo < 2; ++fo)
                vf[k4 * 2 + fo] = *(const short8*)(At +
                    (size_t)(fo * 16 + l16) * Np + k4 * 32 + quad * 8);
        // ---- E(t+1): long MFMA+exp chain covers the V-load latency ----
        if (t < 7) Ephase(t + 1);
        // ---- PV(t): LDS reads + MFMA, V already in registers ----
        int buf = t & 1;
#pragma unroll
        for (int k4 = 0; k4 < 4; ++k4) {
            short8 bfr[4];
#pragma unroll
            for (int fm = 0; fm < 4; ++fm) {
                int row = fm * 16 + l16;
                int si = (row * 128 + k4 * 32 + quad * 8) ^ ((l16 & 7) << 3);
                bfr[fm] = *(const short8*)&P[buf][si];
            }
#pragma unroll
            for (int fo = 0; fo < 2; ++fo)
#pragma unroll
                for (int fm = 0; fm < 4; ++fm)
                    acc[fo][fm] = __builtin_amdgcn_mfma_f32_16x16x32_bf16(
                        vf[k4 * 2 + fo], bfr[fm], acc[fo][fm], 0, 0, 0);
        }
        __syncthreads();
    }
    // ---- epilogue ----
    float g = gamma[0];
#pragma unroll
    for (int fo = 0; fo < 2; ++fo)
#pragma unroll
        for (int fm = 0; fm < 4; ++fm) {
            int m = m0 + fm * 16 + l16;
#pragma unroll
            for (int r = 0; r < 4; ++r) {
                int o = wave * 32 + fo * 16 + quad * 4 + r;
                size_t idx2 = ((size_t)b * Cn + o) * Nn + m;
                out[idx2] = g * (acc[fo][fm][r] + bo[o]) + x[idx2];
            }
        }
}

extern "C" void kernel_launch(void* const* d_in, const int* in_sizes, int n_in,
                              void* d_out, int out_size, void* d_ws, size_t ws_size,
                              hipStream_t stream) {
    (void)in_sizes; (void)n_in; (void)out_size; (void)ws_size;
    const float* x     = (const float*)d_in[0];
    const float* wq    = (const float*)d_in[1];
    const float* bq    = (const float*)d_in[2];
    const float* wk    = (const float*)d_in[3];
    const float* bk    = (const float*)d_in[4];
    const float* wv    = (const float*)d_in[5];
    const float* bv    = (const float*)d_in[6];
    const float* wo    = (const float*)d_in[7];
    const float* bo    = (const float*)d_in[8];
    const float* gamma = (const float*)d_in[9];
    float* out = (float*)d_out;

    float* ws = (float*)d_ws;
    size_t off = 0;
    short* xbfT = (short*)(ws + off); off += (size_t)Bb * Nn * Cn / 2;  // 33.5MB
    short* VpT  = (short*)(ws + off); off += (size_t)Bb * Np * Cn / 2;  //  8.4MB
    short* VoBf = (short*)(ws + off); off += (size_t)Bb * Cn * Np / 2;  //  8.4MB
    short* KT   = (short*)(ws + off); off += (size_t)Bb * Nn * Cs / 2;  //  4.2MB
    short* QpT  = (short*)(ws + off); off += (size_t)Bb * Np * Cs / 2;  //  1.0MB
    float* pS   = ws + off;           off += (size_t)MS2 * Bb * Np;
    float* Ae   = ws + off;           off += (size_t)Bb * Np;
    short* wqBf = (short*)(ws + off); off += (size_t)Cs * Cn / 2;
    short* wkBf = (short*)(ws + off); off += (size_t)Cs * Cn / 2;
    short* wvBf = (short*)(ws + off); off += (size_t)Cn * Cn / 2;
    short* woBf = (short*)(ws + off); off += (size_t)Cn * Cn / 2;

    // fused weight prep (wq pre-scaled by log2 e)
    wprep_k<<<dim3(576), 256, 0, stream>>>(wq, wk, wv, wo, wqBf, wkBf, wvBf, woBf);

    // x -> bf16 transposed [b][m][c]
    xpose_bf<<<dim3(Nn / 64, Cn / 64, Bb), 256, 0, stream>>>(x, xbfT);

    // fused Q/K conv (+Q pool) and V conv (+pool)
    convs_k<<<dim3(512 + 1024), 256, 0, stream>>>(xbfT, wqBf, wkBf, bq, bk,
                                                  wvBf, bv, KT, QpT, VpT);

    // fused rowstats + vo GEMM
    stats_vo_k<<<dim3(1024 + 256), 256, 0, stream>>>(KT, QpT, pS, VpT, woBf, VoBf);

    // combine partials -> Ae
    comb_k<<<dim3(Bb * Np / 256), 256, 0, stream>>>(pS, Ae);

    // fused attention output (E-first verified order + V reg-hoist)
    attn_out_k<<<dim3(1024), 512, 0, stream>>>(KT, QpT, VoBf, Ae,
                                               bo, gamma, x, out);
}